// Round 5
// baseline (66.082 us; speedup 1.0000x reference)
//
#include <hip/hip_runtime.h>

constexpr int NENV = 4096;
constexpr int GD   = 64;
constexpr int RD3  = 192;

typedef __attribute__((ext_vector_type(8))) short s16x8;
typedef __attribute__((ext_vector_type(4))) short s16x4;
typedef __attribute__((ext_vector_type(4))) float f32x4;

__device__ __forceinline__ unsigned short f2bf(float f) {
    unsigned u = __float_as_uint(f);
    u += 0x7FFFu + ((u >> 16) & 1u);
    return (unsigned short)(u >> 16);
}
__device__ __forceinline__ float bf2f(unsigned short u) {
    return __uint_as_float((unsigned)u << 16);
}
__device__ __forceinline__ float sigm(float v) { return 1.f / (1.f + __expf(-v)); }

#define MFMA16(A, B, C) __builtin_amdgcn_mfma_f32_16x16x32_bf16(A, B, C, 0, 0, 0)

// ---- K0: blocks 0..95 cvt W_ih/W_hh -> bf16; block 96 folds Wc^T (bf16) + bc ----
__global__ __launch_bounds__(256) void prep_kernel(
    const float* __restrict__ W_pre, const float* __restrict__ b_pre,
    const float* __restrict__ W_gcn,
    const float* __restrict__ W_ih,  const float* __restrict__ W_hh,
    short* __restrict__ WcTB, float* __restrict__ bcw,
    short* __restrict__ WihB, short* __restrict__ WhhB)
{
    int b = blockIdx.x, t = threadIdx.x;
    if (b == 96) {
        for (int o = t; o < 32 * GD; o += 256) {
            int k = o >> 6, d = o & 63;
            float s = 0.f;
            for (int m = 0; m < GD; ++m) s += W_pre[k * GD + m] * W_gcn[m * GD + d];
            WcTB[d * 32 + k] = (short)f2bf(s);
        }
        if (t < GD) {
            float s = 0.f;
            for (int m = 0; m < GD; ++m) s += b_pre[m] * W_gcn[m * GD + t];
            bcw[t] = s;
        }
    } else {
        int i = b * 256 + t;
        if (i < RD3 * GD) WihB[i] = (short)f2bf(W_ih[i]);
        else              WhhB[i - RD3 * GD] = (short)f2bf(W_hh[i - RD3 * GD]);
    }
}

// ---- fused: ONE WAVE = ONE ENV. 64 threads, zero barriers, 14.1KB LDS. ----------
// LDS map (per block, aggressive same-wave aliasing; all reuse ordered by dataflow):
//   [0,4608)      cnts f32[32][36]   -> yB bf16[32][40] [0,2560) -> hnew f32 stride68 [0,8688)
//   [4608,7168)   xT bf16[32][40]    -> aggB swz bf16[32][64] [4608,8704)
//   [7168,9728)   Ah bf16[32][40]         (aggB/hnew extend over it after last read)
//   [9728,13824)  h0B swz bf16[32][64]
//   [13824,13952) dinv f32[32] ; [13952,14080) rsum f32[32]
__global__ __launch_bounds__(64, 4) void fused_kernel(
    const float* __restrict__ x,      // [4096][32][32]
    const void*  __restrict__ edge,   // [4096][2][256] int32 or int64
    const float* __restrict__ h0f,    // [N][64]
    const float* __restrict__ bcw,    // [64]
    const float* __restrict__ b_gcn,  // [64]
    const short* __restrict__ WcTB,   // [64][32] bf16
    const short* __restrict__ WihB,   // [192][64] bf16
    const short* __restrict__ WhhB,   // [192][64] bf16
    const float* __restrict__ b_ih, const float* __restrict__ b_hh,
    const float* __restrict__ W_out,  // [2048]
    const float* __restrict__ b_out,
    float* __restrict__ value,        // [4096]
    float* __restrict__ hid_out)      // [N][64]
{
    __shared__ __align__(16) char smem[14080];
    float* cnts  = (float*)smem;
    short* yB    = (short*)smem;
    short* xT    = (short*)(smem + 4608);
    short* Ah    = (short*)(smem + 7168);
    char*  aggB  = smem + 4608;
    char*  h0b   = smem + 9728;
    float* sdinv = (float*)(smem + 13824);
    float* srsum = (float*)(smem + 13952);

    const int l   = threadIdx.x;          // 0..63 (one wave)
    const int col = l & 15, lg = l >> 4;
    const int env = blockIdx.x;

    // ================= P0: issue global loads =================
    const int4* pg = (const int4*)edge;   // dtype probe: first 2KB (env 0, shared)
    int4 pa = pg[l], pb = pg[l + 64];
    f32x4 xq[4], hq[8];
    #pragma unroll
    for (int i = 0; i < 4; ++i) xq[i] = ((const f32x4*)(x + (size_t)env * 1024))[l + i * 64];
    #pragma unroll
    for (int i = 0; i < 8; ++i) hq[i] = ((const f32x4*)(h0f + (size_t)env * 2048))[l + i * 64];

    const bool is32 = (__any((pa.y | pa.w | pb.y | pb.w) != 0) != 0);
    int rr_[4], cc_[4];
    if (is32) {
        const int4* e4 = (const int4*)((const char*)edge + (size_t)env * 2048);
        int4 r4 = e4[l], c4 = e4[64 + l];
        rr_[0] = r4.x; rr_[1] = r4.y; rr_[2] = r4.z; rr_[3] = r4.w;
        cc_[0] = c4.x; cc_[1] = c4.y; cc_[2] = c4.z; cc_[3] = c4.w;
    } else {
        const int4* e4 = (const int4*)((const char*)edge + (size_t)env * 4096);
        int4 ra = e4[2 * l], rb = e4[2 * l + 1];
        int4 ca = e4[128 + 2 * l], cb = e4[128 + 2 * l + 1];
        rr_[0] = ra.x; rr_[1] = ra.z; rr_[2] = rb.x; rr_[3] = rb.z;
        cc_[0] = ca.x; cc_[1] = ca.z; cc_[2] = cb.x; cc_[3] = cb.z;
    }

    // ================= P1: zero counts, stage xT / h0B =================
    #pragma unroll
    for (int i = 0; i < 5; ++i) {
        int o = l + i * 64;
        if (o < 288) ((f32x4*)cnts)[o] = (f32x4){0.f, 0.f, 0.f, 0.f};
    }
    #pragma unroll
    for (int i = 0; i < 4; ++i) {         // x -> xT bf16 (feature-major)
        int idx4 = l + i * 64;
        int n = idx4 >> 3, q = idx4 & 7;
        #pragma unroll
        for (int j = 0; j < 4; ++j) xT[(q * 4 + j) * 40 + n] = (short)f2bf(xq[i][j]);
    }
    #pragma unroll
    for (int i = 0; i < 8; ++i) {         // h0 -> swizzled bf16 rows (128B)
        int idx4 = l + i * 64;
        int n = idx4 >> 4, q = idx4 & 15;
        s16x4 pk;
        pk[0] = (short)f2bf(hq[i][0]); pk[1] = (short)f2bf(hq[i][1]);
        pk[2] = (short)f2bf(hq[i][2]); pk[3] = (short)f2bf(hq[i][3]);
        *(s16x4*)(h0b + n * 128 + ((q * 8) ^ ((n & 7) << 4))) = pk;
    }

    // ================= P2: adjacency counts (wave-local atomics) =================
    #pragma unroll
    for (int j = 0; j < 4; ++j) atomicAdd(cnts + cc_[j] * 36 + rr_[j], 1.0f);

    // ================= P3: degree + dinv (2 lanes per target row) ================
    const int c_  = l >> 1;
    const int r0_ = (l & 1) * 16;
    f32x4 cv[4];
    float s16s = 0.f;
    #pragma unroll
    for (int q = 0; q < 4; ++q) {
        cv[q] = *(const f32x4*)(cnts + c_ * 36 + r0_ + q * 4);
        s16s += cv[q][0] + cv[q][1] + cv[q][2] + cv[q][3];
    }
    float degs = s16s + __shfl_xor(s16s, 1, 64);
    float dc = rsqrtf(1.0f + degs);
    if (!(l & 1)) sdinv[c_] = dc;

    // ================= P4: normalize -> Ah bf16, rowsum ==========================
    {
        f32x4 dv[4];
        #pragma unroll
        for (int q = 0; q < 4; ++q) dv[q] = *(const f32x4*)(sdinv + r0_ + q * 4);
        float dot = 0.f;
        s16x8 o0, o1;
        #pragma unroll
        for (int k = 0; k < 16; ++k) {
            float u = cv[k >> 2][k & 3] * dv[k >> 2][k & 3];
            dot += u;
            float v = u * dc;
            if (r0_ + k == c_) v += dc * dc;
            if (k < 8) o0[k] = (short)f2bf(v); else o1[k - 8] = (short)f2bf(v);
        }
        dot += __shfl_xor(dot, 1, 64);
        if (!(l & 1)) srsum[c_] = dc * dot + dc * dc;
        *(s16x8*)(Ah + c_ * 40 + r0_)     = o0;
        *(s16x8*)(Ah + c_ * 40 + r0_ + 8) = o1;
    }

    // ================= P5: yT = xT @ AhatT (4 MFMA) -> yB[node][feat] ============
    {
        s16x8 Ax0 = *(const s16x8*)(xT + col * 40 + lg * 8);
        s16x8 Ax1 = *(const s16x8*)(xT + (16 + col) * 40 + lg * 8);
        s16x8 Bh0 = *(const s16x8*)(Ah + col * 40 + lg * 8);
        s16x8 Bh1 = *(const s16x8*)(Ah + (16 + col) * 40 + lg * 8);
        f32x4 y00 = {}, y01 = {}, y10 = {}, y11 = {};
        y00 = MFMA16(Ax0, Bh0, y00);
        y01 = MFMA16(Ax0, Bh1, y01);
        y10 = MFMA16(Ax1, Bh0, y10);
        y11 = MFMA16(Ax1, Bh1, y11);
        #pragma unroll
        for (int f = 0; f < 2; ++f)
            #pragma unroll
            for (int d = 0; d < 2; ++d) {
                f32x4 a = (f == 0) ? (d == 0 ? y00 : y01) : (d == 0 ? y10 : y11);
                s16x4 pk;
                pk[0] = (short)f2bf(a[0]); pk[1] = (short)f2bf(a[1]);
                pk[2] = (short)f2bf(a[2]); pk[3] = (short)f2bf(a[3]);
                *(s16x4*)(yB + (d * 16 + col) * 40 + f * 16 + lg * 4) = pk;
            }
    }

    // ================= P6: aggT = WcT @ yT (8 MFMA) -> aggB swz ==================
    {
        s16x8 Aw[4];
        #pragma unroll
        for (int a = 0; a < 4; ++a)
            Aw[a] = *(const s16x8*)(WcTB + (a * 16 + col) * 32 + lg * 8);
        s16x8 By0 = *(const s16x8*)(yB + col * 40 + lg * 8);
        s16x8 By1 = *(const s16x8*)(yB + (16 + col) * 40 + lg * 8);
        float rs0 = srsum[col], rs1 = srsum[16 + col];
        #pragma unroll
        for (int a = 0; a < 4; ++a) {
            f32x4 g0 = {}, g1 = {};
            g0 = MFMA16(Aw[a], By0, g0);
            g1 = MFMA16(Aw[a], By1, g1);
            f32x4 bc4 = *(const f32x4*)(bcw + a * 16 + lg * 4);
            f32x4 bg4 = *(const f32x4*)(b_gcn + a * 16 + lg * 4);
            #pragma unroll
            for (int n = 0; n < 2; ++n) {
                f32x4 g = n ? g1 : g0;
                float rs = n ? rs1 : rs0;
                int node = n * 16 + col;
                s16x4 pk;
                #pragma unroll
                for (int r = 0; r < 4; ++r) pk[r] = (short)f2bf(g[r] + rs * bc4[r] + bg4[r]);
                *(s16x4*)(aggB + node * 128 + ((a * 32 + lg * 8) ^ ((node & 7) << 4))) = pk;
            }
        }
    }

    // ================= P7: GRU — whole env in this wave ==========================
    s16x8 Ba[4], Bh[4];                   // [kt*2+nt]
    #pragma unroll
    for (int kt = 0; kt < 2; ++kt)
        #pragma unroll
        for (int nt = 0; nt < 2; ++nt) {
            int node = nt * 16 + col;
            int off = node * 128 + ((kt * 64 + lg * 16) ^ ((node & 7) << 4));
            Ba[kt * 2 + nt] = *(const s16x8*)(aggB + off);
            Bh[kt * 2 + nt] = *(const s16x8*)(h0b + off);
        }

    #pragma unroll
    for (int dt = 0; dt < 4; ++dt) {
        f32x4 ar[2] = {}, az[2] = {}, ain[2] = {}, ahn[2] = {};
        __builtin_amdgcn_s_setprio(1);
        #pragma unroll
        for (int g = 0; g < 3; ++g) {
            const int wr = (g * 64 + dt * 16 + col) * 64 + lg * 8;
            s16x8 Wi0 = *(const s16x8*)(WihB + wr);
            s16x8 Wi1 = *(const s16x8*)(WihB + wr + 32);
            s16x8 Wh0 = *(const s16x8*)(WhhB + wr);
            s16x8 Wh1 = *(const s16x8*)(WhhB + wr + 32);
            #pragma unroll
            for (int nt = 0; nt < 2; ++nt) {
                if (g == 0) {
                    ar[nt] = MFMA16(Wi0, Ba[nt], ar[nt]);
                    ar[nt] = MFMA16(Wi1, Ba[2 + nt], ar[nt]);
                    ar[nt] = MFMA16(Wh0, Bh[nt], ar[nt]);
                    ar[nt] = MFMA16(Wh1, Bh[2 + nt], ar[nt]);
                } else if (g == 1) {
                    az[nt] = MFMA16(Wi0, Ba[nt], az[nt]);
                    az[nt] = MFMA16(Wi1, Ba[2 + nt], az[nt]);
                    az[nt] = MFMA16(Wh0, Bh[nt], az[nt]);
                    az[nt] = MFMA16(Wh1, Bh[2 + nt], az[nt]);
                } else {
                    ain[nt] = MFMA16(Wi0, Ba[nt], ain[nt]);
                    ain[nt] = MFMA16(Wi1, Ba[2 + nt], ain[nt]);
                    ahn[nt] = MFMA16(Wh0, Bh[nt], ahn[nt]);
                    ahn[nt] = MFMA16(Wh1, Bh[2 + nt], ahn[nt]);
                }
            }
        }
        __builtin_amdgcn_s_setprio(0);
        // epilogue for d-slice dt*16+lg*4 .. +4
        const int db = dt * 16 + lg * 4;
        f32x4 br  = *(const f32x4*)(b_ih + db);
        f32x4 bz  = *(const f32x4*)(b_ih + 64 + db);
        f32x4 bin = *(const f32x4*)(b_ih + 128 + db);
        f32x4 bhn = *(const f32x4*)(b_hh + 128 + db);
        {
            f32x4 t1 = *(const f32x4*)(b_hh + db);
            f32x4 t2 = *(const f32x4*)(b_hh + 64 + db);
            br += t1; bz += t2;
        }
        #pragma unroll
        for (int nt = 0; nt < 2; ++nt) {
            int node = nt * 16 + col;
            s16x4 h04 = *(const s16x4*)(h0b + node * 128 + ((dt * 32 + lg * 8) ^ ((node & 7) << 4)));
            f32x4 out;
            #pragma unroll
            for (int r = 0; r < 4; ++r) {
                float rg = sigm(ar[nt][r] + br[r]);
                float zg = sigm(az[nt][r] + bz[r]);
                float e2 = __expf(2.f * (ain[nt][r] + bin[r] + rg * (ahn[nt][r] + bhn[r])));
                float ng = 1.f - 2.f / (e2 + 1.f);
                out[r] = (1.f - zg) * ng + zg * bf2f((unsigned short)h04[r]);
            }
            *(f32x4*)(smem + node * 272 + db * 4) = out;   // hnew, stride 68 f32
        }
    }

    // ================= P8: flush + value head ====================================
    {
        float* ho = hid_out + (size_t)env * 2048;
        float vsum = 0.f;
        #pragma unroll
        for (int i = 0; i < 8; ++i) {
            int idx4 = l + i * 64;
            int node = idx4 >> 4, q = idx4 & 15;
            f32x4 hv = *(const f32x4*)(smem + node * 272 + q * 16);
            ((f32x4*)ho)[idx4] = hv;
            f32x4 wv = ((const f32x4*)W_out)[idx4];
            vsum += hv[0] * wv[0] + hv[1] * wv[1] + hv[2] * wv[2] + hv[3] * wv[3];
        }
        #pragma unroll
        for (int off = 32; off > 0; off >>= 1) vsum += __shfl_down(vsum, off, 64);
        if (l == 0) value[env] = vsum + b_out[0];
    }
}

// ---------------------------------------------------------------------------------
extern "C" void kernel_launch(void* const* d_in, const int* in_sizes, int n_in,
                              void* d_out, int out_size, void* d_ws, size_t ws_size,
                              hipStream_t stream)
{
    const float* x     = (const float*)d_in[0];
    const void*  edge  = d_in[1];
    const float* h0    = (const float*)d_in[2];
    const float* W_pre = (const float*)d_in[3];
    const float* b_pre = (const float*)d_in[4];
    const float* W_gcn = (const float*)d_in[5];
    const float* b_gcn = (const float*)d_in[6];
    const float* W_ih  = (const float*)d_in[7];
    const float* W_hh  = (const float*)d_in[8];
    const float* b_ih  = (const float*)d_in[9];
    const float* b_hh  = (const float*)d_in[10];
    const float* W_out = (const float*)d_in[11];
    const float* b_out = (const float*)d_in[12];

    float* value = (float*)d_out;
    float* hid   = (float*)d_out + NENV;

    short* WcTB = (short*)d_ws;                          // 2048 bf16
    float* bcw  = (float*)((char*)d_ws + 4096);          // 64 f32
    short* WihB = (short*)((char*)d_ws + 4608);          // 12288 bf16
    short* WhhB = WihB + RD3 * GD;                       // 12288 bf16

    prep_kernel<<<97, 256, 0, stream>>>(W_pre, b_pre, W_gcn, W_ih, W_hh,
                                        WcTB, bcw, WihB, WhhB);
    fused_kernel<<<NENV, 64, 0, stream>>>(x, edge, h0, bcw, b_gcn, WcTB,
                                          WihB, WhhB, b_ih, b_hh,
                                          W_out, b_out, value, hid);
}

// Round 6
// 64.745 us; speedup vs baseline: 1.0207x; 1.0207x over previous
//
#include <hip/hip_runtime.h>

constexpr int NENV = 4096;
constexpr int GD   = 64;
constexpr int RD3  = 192;

typedef __attribute__((ext_vector_type(8))) short s16x8;
typedef __attribute__((ext_vector_type(4))) short s16x4;
typedef __attribute__((ext_vector_type(4))) float f32x4;

__device__ __forceinline__ unsigned short f2bf(float f) {
    unsigned u = __float_as_uint(f);
    u += 0x7FFFu + ((u >> 16) & 1u);
    return (unsigned short)(u >> 16);
}
__device__ __forceinline__ float sigm(float v) { return 1.f / (1.f + __expf(-v)); }

__device__ __forceinline__ s16x8 cvt8(const float* p) {
    f32x4 a = *(const f32x4*)p;
    f32x4 b = *(const f32x4*)(p + 4);
    s16x8 r;
    r[0] = (short)f2bf(a[0]); r[1] = (short)f2bf(a[1]);
    r[2] = (short)f2bf(a[2]); r[3] = (short)f2bf(a[3]);
    r[4] = (short)f2bf(b[0]); r[5] = (short)f2bf(b[1]);
    r[6] = (short)f2bf(b[2]); r[7] = (short)f2bf(b[3]);
    return r;
}

#define MFMA16(A, B, C) __builtin_amdgcn_mfma_f32_16x16x32_bf16(A, B, C, 0, 0, 0)

// ---- K0: blocks 0..95 cvt W_ih/W_hh -> bf16; block 96 folds Wc^T (bf16) + bc ----
__global__ __launch_bounds__(256) void prep_kernel(
    const float* __restrict__ W_pre, const float* __restrict__ b_pre,
    const float* __restrict__ W_gcn,
    const float* __restrict__ W_ih,  const float* __restrict__ W_hh,
    short* __restrict__ WcTB, float* __restrict__ bcw,
    short* __restrict__ WihB, short* __restrict__ WhhB)
{
    int b = blockIdx.x, t = threadIdx.x;
    if (b == 96) {
        for (int o = t; o < 32 * GD; o += 256) {
            int k = o >> 6, d = o & 63;
            float s = 0.f;
            for (int m = 0; m < GD; ++m) s += W_pre[k * GD + m] * W_gcn[m * GD + d];
            WcTB[d * 32 + k] = (short)f2bf(s);
        }
        if (t < GD) {
            float s = 0.f;
            for (int m = 0; m < GD; ++m) s += b_pre[m] * W_gcn[m * GD + t];
            bcw[t] = s;
        }
    } else {
        int i = b * 256 + t;
        if (i < RD3 * GD) WihB[i] = (short)f2bf(W_ih[i]);
        else              WhhB[i - RD3 * GD] = (short)f2bf(W_hh[i - RD3 * GD]);
    }
}

// ---- fused: 4 INDEPENDENT waves/block, wave = env, ZERO barriers, 39.9KB LDS ----
// Per-env LDS (stride 9984B), aggressive same-wave aliasing (dataflow-ordered):
//   [0,4608)     cnts f32[32][36]  -> yB bf16[32][40] [0,2560)
//   [4608,7168)  xT bf16[32][40] --\
//   [7168,9728)  Ah bf16[32][40] ---> aggB swz bf16[32][64] [4608,8704) after P5
//   [9728,9856)  dinv f32[32] ; [9856,9984) rsum f32[32]
// h0 fragments: global->regs (no LDS). hnew: regs->global direct (no LDS).
__global__ __launch_bounds__(256, 4) void fused_kernel(
    const float* __restrict__ x,      // [4096][32][32]
    const void*  __restrict__ edge,   // [4096][2][256] int32 or int64
    const float* __restrict__ h0f,    // [N][64]
    const float* __restrict__ bcw,    // [64]
    const float* __restrict__ b_gcn,  // [64]
    const short* __restrict__ WcTB,   // [64][32] bf16
    const short* __restrict__ WihB,   // [192][64] bf16
    const short* __restrict__ WhhB,   // [192][64] bf16
    const float* __restrict__ b_ih, const float* __restrict__ b_hh,
    const float* __restrict__ W_out,  // [2048]
    const float* __restrict__ b_out,
    float* __restrict__ value,        // [4096]
    float* __restrict__ hid_out)      // [N][64]
{
    __shared__ __align__(16) char smem[39936];

    const int t   = threadIdx.x;
    const int w   = t >> 6;
    const int l   = t & 63;
    const int col = l & 15, lg = l >> 4;
    const int env = blockIdx.x * 4 + w;

    char*  eb    = smem + w * 9984;
    float* cnts  = (float*)eb;
    short* yB    = (short*)eb;
    short* xT    = (short*)(eb + 4608);
    short* Ah    = (short*)(eb + 7168);
    char*  aggB  = eb + 4608;
    float* sdinv = (float*)(eb + 9728);
    float* srsum = (float*)(eb + 9856);

    // ================= P0: issue global loads =================
    const int4* pg = (const int4*)edge;   // dtype probe (first 2KB, env 0)
    int4 pa = pg[l], pb = pg[l + 64];
    f32x4 xq[4];
    #pragma unroll
    for (int i = 0; i < 4; ++i) xq[i] = ((const f32x4*)(x + (size_t)env * 1024))[l + i * 64];

    const float* h0e = h0f + (size_t)env * 2048;
    s16x8 Hb[4];                          // GRU h0 B-fragments straight from global
    #pragma unroll
    for (int kt = 0; kt < 2; ++kt)
        #pragma unroll
        for (int nt = 0; nt < 2; ++nt)
            Hb[kt * 2 + nt] = cvt8(h0e + (nt * 16 + col) * 64 + kt * 32 + lg * 8);

    const bool is32 = (__any((pa.y | pa.w | pb.y | pb.w) != 0) != 0);
    int rr_[4], cc_[4];
    if (is32) {
        const int4* e4 = (const int4*)((const char*)edge + (size_t)env * 2048);
        int4 r4 = e4[l], c4 = e4[64 + l];
        rr_[0] = r4.x; rr_[1] = r4.y; rr_[2] = r4.z; rr_[3] = r4.w;
        cc_[0] = c4.x; cc_[1] = c4.y; cc_[2] = c4.z; cc_[3] = c4.w;
    } else {
        const int4* e4 = (const int4*)((const char*)edge + (size_t)env * 4096);
        int4 ra = e4[2 * l], rb = e4[2 * l + 1];
        int4 ca = e4[128 + 2 * l], cb = e4[128 + 2 * l + 1];
        rr_[0] = ra.x; rr_[1] = ra.z; rr_[2] = rb.x; rr_[3] = rb.z;
        cc_[0] = ca.x; cc_[1] = ca.z; cc_[2] = cb.x; cc_[3] = cb.z;
    }

    // ================= P1: zero counts, stage xT =================
    #pragma unroll
    for (int i = 0; i < 5; ++i) {
        int o = l + i * 64;
        if (o < 288) ((f32x4*)cnts)[o] = (f32x4){0.f, 0.f, 0.f, 0.f};
    }
    #pragma unroll
    for (int i = 0; i < 4; ++i) {         // x -> xT bf16 (feature-major)
        int idx4 = l + i * 64;
        int n = idx4 >> 3, q = idx4 & 7;
        #pragma unroll
        for (int j = 0; j < 4; ++j) xT[(q * 4 + j) * 40 + n] = (short)f2bf(xq[i][j]);
    }

    // ================= P2: adjacency counts (wave-local atomics) =================
    #pragma unroll
    for (int j = 0; j < 4; ++j) atomicAdd(cnts + cc_[j] * 36 + rr_[j], 1.0f);

    // ================= P3: degree + dinv (2 lanes per target row) ================
    const int c_  = l >> 1;
    const int r0_ = (l & 1) * 16;
    f32x4 cv[4];
    float s16s = 0.f;
    #pragma unroll
    for (int q = 0; q < 4; ++q) {
        cv[q] = *(const f32x4*)(cnts + c_ * 36 + r0_ + q * 4);
        s16s += cv[q][0] + cv[q][1] + cv[q][2] + cv[q][3];
    }
    float degs = s16s + __shfl_xor(s16s, 1, 64);
    float dc = rsqrtf(1.0f + degs);
    if (!(l & 1)) sdinv[c_] = dc;

    // ================= P4: normalize -> Ah bf16, rowsum ==========================
    {
        f32x4 dv[4];
        #pragma unroll
        for (int q = 0; q < 4; ++q) dv[q] = *(const f32x4*)(sdinv + r0_ + q * 4);
        float dot = 0.f;
        s16x8 o0, o1;
        #pragma unroll
        for (int k = 0; k < 16; ++k) {
            float u = cv[k >> 2][k & 3] * dv[k >> 2][k & 3];
            dot += u;
            float v = u * dc;
            if (r0_ + k == c_) v += dc * dc;
            if (k < 8) o0[k] = (short)f2bf(v); else o1[k - 8] = (short)f2bf(v);
        }
        dot += __shfl_xor(dot, 1, 64);
        if (!(l & 1)) srsum[c_] = dc * dot + dc * dc;
        *(s16x8*)(Ah + c_ * 40 + r0_)     = o0;
        *(s16x8*)(Ah + c_ * 40 + r0_ + 8) = o1;
    }

    // ================= P5: yT = xT @ AhatT (4 MFMA) -> yB[node][feat] ============
    {
        s16x8 Ax0 = *(const s16x8*)(xT + col * 40 + lg * 8);
        s16x8 Ax1 = *(const s16x8*)(xT + (16 + col) * 40 + lg * 8);
        s16x8 Af0 = *(const s16x8*)(Ah + col * 40 + lg * 8);
        s16x8 Af1 = *(const s16x8*)(Ah + (16 + col) * 40 + lg * 8);
        f32x4 y00 = {}, y01 = {}, y10 = {}, y11 = {};
        y00 = MFMA16(Ax0, Af0, y00);
        y01 = MFMA16(Ax0, Af1, y01);
        y10 = MFMA16(Ax1, Af0, y10);
        y11 = MFMA16(Ax1, Af1, y11);
        #pragma unroll
        for (int f = 0; f < 2; ++f)
            #pragma unroll
            for (int d = 0; d < 2; ++d) {
                f32x4 a = (f == 0) ? (d == 0 ? y00 : y01) : (d == 0 ? y10 : y11);
                s16x4 pk;
                pk[0] = (short)f2bf(a[0]); pk[1] = (short)f2bf(a[1]);
                pk[2] = (short)f2bf(a[2]); pk[3] = (short)f2bf(a[3]);
                *(s16x4*)(yB + (d * 16 + col) * 40 + f * 16 + lg * 4) = pk;
            }
    }

    // ================= P6: aggT = WcT @ yT (8 MFMA) -> aggB swz ==================
    {
        s16x8 Aw[4];
        #pragma unroll
        for (int a = 0; a < 4; ++a)
            Aw[a] = *(const s16x8*)(WcTB + (a * 16 + col) * 32 + lg * 8);
        s16x8 By0 = *(const s16x8*)(yB + col * 40 + lg * 8);
        s16x8 By1 = *(const s16x8*)(yB + (16 + col) * 40 + lg * 8);
        float rs0 = srsum[col], rs1 = srsum[16 + col];
        #pragma unroll
        for (int a = 0; a < 4; ++a) {
            f32x4 g0 = {}, g1 = {};
            g0 = MFMA16(Aw[a], By0, g0);
            g1 = MFMA16(Aw[a], By1, g1);
            f32x4 bc4 = *(const f32x4*)(bcw + a * 16 + lg * 4);
            f32x4 bg4 = *(const f32x4*)(b_gcn + a * 16 + lg * 4);
            #pragma unroll
            for (int n = 0; n < 2; ++n) {
                f32x4 g = n ? g1 : g0;
                float rs = n ? rs1 : rs0;
                int node = n * 16 + col;
                s16x4 pk;
                #pragma unroll
                for (int r = 0; r < 4; ++r) pk[r] = (short)f2bf(g[r] + rs * bc4[r] + bg4[r]);
                *(s16x4*)(aggB + node * 128 + ((a * 32 + lg * 8) ^ ((node & 7) << 4))) = pk;
            }
        }
    }

    // ================= P7: GRU (whole env in-wave) + fused epilogue/flush ========
    s16x8 Ba[4];
    #pragma unroll
    for (int kt = 0; kt < 2; ++kt)
        #pragma unroll
        for (int nt = 0; nt < 2; ++nt) {
            int node = nt * 16 + col;
            Ba[kt * 2 + nt] = *(const s16x8*)(aggB + node * 128 +
                                              ((kt * 64 + lg * 16) ^ ((node & 7) << 4)));
        }

    float* ho = hid_out + (size_t)env * 2048;
    float vsum = 0.f;

    #pragma unroll
    for (int dt = 0; dt < 4; ++dt) {
        f32x4 ar[2] = {}, az[2] = {}, ain[2] = {}, ahn[2] = {};
        __builtin_amdgcn_s_setprio(1);
        #pragma unroll
        for (int g = 0; g < 3; ++g) {
            const int wr = (g * 64 + dt * 16 + col) * 64 + lg * 8;
            s16x8 Wi0 = *(const s16x8*)(WihB + wr);
            s16x8 Wi1 = *(const s16x8*)(WihB + wr + 32);
            s16x8 Wh0 = *(const s16x8*)(WhhB + wr);
            s16x8 Wh1 = *(const s16x8*)(WhhB + wr + 32);
            #pragma unroll
            for (int nt = 0; nt < 2; ++nt) {
                if (g == 0) {
                    ar[nt] = MFMA16(Wi0, Ba[nt], ar[nt]);
                    ar[nt] = MFMA16(Wi1, Ba[2 + nt], ar[nt]);
                    ar[nt] = MFMA16(Wh0, Hb[nt], ar[nt]);
                    ar[nt] = MFMA16(Wh1, Hb[2 + nt], ar[nt]);
                } else if (g == 1) {
                    az[nt] = MFMA16(Wi0, Ba[nt], az[nt]);
                    az[nt] = MFMA16(Wi1, Ba[2 + nt], az[nt]);
                    az[nt] = MFMA16(Wh0, Hb[nt], az[nt]);
                    az[nt] = MFMA16(Wh1, Hb[2 + nt], az[nt]);
                } else {
                    ain[nt] = MFMA16(Wi0, Ba[nt], ain[nt]);
                    ain[nt] = MFMA16(Wi1, Ba[2 + nt], ain[nt]);
                    ahn[nt] = MFMA16(Wh0, Hb[nt], ahn[nt]);
                    ahn[nt] = MFMA16(Wh1, Hb[2 + nt], ahn[nt]);
                }
            }
        }
        __builtin_amdgcn_s_setprio(0);

        const int db = dt * 16 + lg * 4;
        f32x4 br  = *(const f32x4*)(b_ih + db);
        f32x4 bz  = *(const f32x4*)(b_ih + 64 + db);
        f32x4 bin = *(const f32x4*)(b_ih + 128 + db);
        f32x4 bhn = *(const f32x4*)(b_hh + 128 + db);
        {
            f32x4 t1 = *(const f32x4*)(b_hh + db);
            f32x4 t2 = *(const f32x4*)(b_hh + 64 + db);
            br += t1; bz += t2;
        }
        #pragma unroll
        for (int nt = 0; nt < 2; ++nt) {
            int node = nt * 16 + col;
            f32x4 h04 = *(const f32x4*)(h0e + node * 64 + db);   // L1/L2-hot reload
            f32x4 wv  = *(const f32x4*)(W_out + node * 64 + db);
            f32x4 out;
            #pragma unroll
            for (int r = 0; r < 4; ++r) {
                float rg = sigm(ar[nt][r] + br[r]);
                float zg = sigm(az[nt][r] + bz[r]);
                float e2 = __expf(2.f * (ain[nt][r] + bin[r] + rg * (ahn[nt][r] + bhn[r])));
                float ng = 1.f - 2.f / (e2 + 1.f);
                out[r] = (1.f - zg) * ng + zg * h04[r];
            }
            *(f32x4*)(ho + node * 64 + db) = out;                // direct flush
            vsum += out[0] * wv[0] + out[1] * wv[1] + out[2] * wv[2] + out[3] * wv[3];
        }
    }

    // ================= P8: value reduce ==========================================
    #pragma unroll
    for (int off = 32; off > 0; off >>= 1) vsum += __shfl_down(vsum, off, 64);
    if (l == 0) value[env] = vsum + b_out[0];
}

// ---------------------------------------------------------------------------------
extern "C" void kernel_launch(void* const* d_in, const int* in_sizes, int n_in,
                              void* d_out, int out_size, void* d_ws, size_t ws_size,
                              hipStream_t stream)
{
    const float* x     = (const float*)d_in[0];
    const void*  edge  = d_in[1];
    const float* h0    = (const float*)d_in[2];
    const float* W_pre = (const float*)d_in[3];
    const float* b_pre = (const float*)d_in[4];
    const float* W_gcn = (const float*)d_in[5];
    const float* b_gcn = (const float*)d_in[6];
    const float* W_ih  = (const float*)d_in[7];
    const float* W_hh  = (const float*)d_in[8];
    const float* b_ih  = (const float*)d_in[9];
    const float* b_hh  = (const float*)d_in[10];
    const float* W_out = (const float*)d_in[11];
    const float* b_out = (const float*)d_in[12];

    float* value = (float*)d_out;
    float* hid   = (float*)d_out + NENV;

    short* WcTB = (short*)d_ws;                          // 2048 bf16
    float* bcw  = (float*)((char*)d_ws + 4096);          // 64 f32
    short* WihB = (short*)((char*)d_ws + 4608);          // 12288 bf16
    short* WhhB = WihB + RD3 * GD;                       // 12288 bf16

    prep_kernel<<<97, 256, 0, stream>>>(W_pre, b_pre, W_gcn, W_ih, W_hh,
                                        WcTB, bcw, WihB, WhhB);
    fused_kernel<<<NENV / 4, 256, 0, stream>>>(x, edge, h0, bcw, b_gcn, WcTB,
                                               WihB, WhhB, b_ih, b_hh,
                                               W_out, b_out, value, hid);
}

// Round 7
// 64.392 us; speedup vs baseline: 1.0263x; 1.0055x over previous
//
#include <hip/hip_runtime.h>

constexpr int NENV = 4096;
constexpr int GD   = 64;
constexpr int RD3  = 192;

typedef __attribute__((ext_vector_type(8))) short s16x8;
typedef __attribute__((ext_vector_type(4))) short s16x4;
typedef __attribute__((ext_vector_type(4))) float f32x4;

__device__ __forceinline__ unsigned short f2bf(float f) {
    unsigned u = __float_as_uint(f);
    u += 0x7FFFu + ((u >> 16) & 1u);
    return (unsigned short)(u >> 16);
}
__device__ __forceinline__ float sigm(float v) { return 1.f / (1.f + __expf(-v)); }

__device__ __forceinline__ s16x8 cvt8(const float* p) {
    f32x4 a = *(const f32x4*)p;
    f32x4 b = *(const f32x4*)(p + 4);
    s16x8 r;
    r[0] = (short)f2bf(a[0]); r[1] = (short)f2bf(a[1]);
    r[2] = (short)f2bf(a[2]); r[3] = (short)f2bf(a[3]);
    r[4] = (short)f2bf(b[0]); r[5] = (short)f2bf(b[1]);
    r[6] = (short)f2bf(b[2]); r[7] = (short)f2bf(b[3]);
    return r;
}

#define MFMA16(A, B, C) __builtin_amdgcn_mfma_f32_16x16x32_bf16(A, B, C, 0, 0, 0)

// ---- K0: blocks 0..95 cvt W_ih/W_hh -> bf16; block 96 folds Wc^T (bf16) + bc ----
__global__ __launch_bounds__(256) void prep_kernel(
    const float* __restrict__ W_pre, const float* __restrict__ b_pre,
    const float* __restrict__ W_gcn,
    const float* __restrict__ W_ih,  const float* __restrict__ W_hh,
    short* __restrict__ WcTB, float* __restrict__ bcw,
    short* __restrict__ WihB, short* __restrict__ WhhB)
{
    int b = blockIdx.x, t = threadIdx.x;
    if (b == 96) {
        for (int o = t; o < 32 * GD; o += 256) {
            int k = o >> 6, d = o & 63;
            float s = 0.f;
            for (int m = 0; m < GD; ++m) s += W_pre[k * GD + m] * W_gcn[m * GD + d];
            WcTB[d * 32 + k] = (short)f2bf(s);
        }
        if (t < GD) {
            float s = 0.f;
            for (int m = 0; m < GD; ++m) s += b_pre[m] * W_gcn[m * GD + t];
            bcw[t] = s;
        }
    } else {
        int i = b * 256 + t;
        if (i < RD3 * GD) WihB[i] = (short)f2bf(W_ih[i]);
        else              WhhB[i - RD3 * GD] = (short)f2bf(W_hh[i - RD3 * GD]);
    }
}

// ---- fused: 4 independent waves/block, wave = env, zero barriers, 39.9KB LDS ----
// Per-env LDS (stride 9984B), same-wave aliasing (dataflow-ordered):
//   [0,4608)     cnts f32[32][36]  -> yB bf16[32][40] [0,2560) --\
//   [4608,7168)  xT bf16[32][40] --\                              -> hnew f32
//   [7168,9728)  Ah bf16[32][40] ---> aggB swz bf16[32][64]          [0,8704)
//   [9728,9856)  dinv f32[32] ; [9856,9984) rsum f32[32]
__global__ __launch_bounds__(256, 3) void fused_kernel(
    const float* __restrict__ x,      // [4096][32][32]
    const void*  __restrict__ edge,   // [4096][2][256] int32 or int64
    const float* __restrict__ h0f,    // [N][64]
    const float* __restrict__ bcw,    // [64]
    const float* __restrict__ b_gcn,  // [64]
    const short* __restrict__ WcTB,   // [64][32] bf16
    const short* __restrict__ WihB,   // [192][64] bf16
    const short* __restrict__ WhhB,   // [192][64] bf16
    const float* __restrict__ b_ih, const float* __restrict__ b_hh,
    const float* __restrict__ W_out,  // [2048]
    const float* __restrict__ b_out,
    float* __restrict__ value,        // [4096]
    float* __restrict__ hid_out)      // [N][64]
{
    __shared__ __align__(16) char smem[39936];

    const int t   = threadIdx.x;
    const int w   = t >> 6;
    const int l   = t & 63;
    const int col = l & 15, lg = l >> 4;
    const int env = blockIdx.x * 4 + w;

    char*  eb    = smem + w * 9984;
    float* cnts  = (float*)eb;
    short* yB    = (short*)eb;
    short* xT    = (short*)(eb + 4608);
    short* Ah    = (short*)(eb + 7168);
    char*  aggB  = eb + 4608;
    float* sdinv = (float*)(eb + 9728);
    float* srsum = (float*)(eb + 9856);

    // ================= P0: issue global loads =================
    const int4* pg = (const int4*)edge;   // dtype probe (first 2KB)
    int4 pa = pg[l], pb = pg[l + 64];
    f32x4 xq[4];
    #pragma unroll
    for (int i = 0; i < 4; ++i) xq[i] = ((const f32x4*)(x + (size_t)env * 1024))[l + i * 64];

    const float* h0e = h0f + (size_t)env * 2048;
    s16x8 Hb[4];                          // GRU h0 B-fragments from global
    #pragma unroll
    for (int kt = 0; kt < 2; ++kt)
        #pragma unroll
        for (int nt = 0; nt < 2; ++nt)
            Hb[kt * 2 + nt] = cvt8(h0e + (nt * 16 + col) * 64 + kt * 32 + lg * 8);

    const bool is32 = (__any((pa.y | pa.w | pb.y | pb.w) != 0) != 0);
    int rr_[4], cc_[4];
    if (is32) {
        const int4* e4 = (const int4*)((const char*)edge + (size_t)env * 2048);
        int4 r4 = e4[l], c4 = e4[64 + l];
        rr_[0] = r4.x; rr_[1] = r4.y; rr_[2] = r4.z; rr_[3] = r4.w;
        cc_[0] = c4.x; cc_[1] = c4.y; cc_[2] = c4.z; cc_[3] = c4.w;
    } else {
        const int4* e4 = (const int4*)((const char*)edge + (size_t)env * 4096);
        int4 ra = e4[2 * l], rb = e4[2 * l + 1];
        int4 ca = e4[128 + 2 * l], cb = e4[128 + 2 * l + 1];
        rr_[0] = ra.x; rr_[1] = ra.z; rr_[2] = rb.x; rr_[3] = rb.z;
        cc_[0] = ca.x; cc_[1] = ca.z; cc_[2] = cb.x; cc_[3] = cb.z;
    }

    // ================= P1: zero counts, stage xT =================
    #pragma unroll
    for (int i = 0; i < 5; ++i) {
        int o = l + i * 64;
        if (o < 288) ((f32x4*)cnts)[o] = (f32x4){0.f, 0.f, 0.f, 0.f};
    }
    #pragma unroll
    for (int i = 0; i < 4; ++i) {         // x -> xT bf16 (feature-major)
        int idx4 = l + i * 64;
        int n = idx4 >> 3, q = idx4 & 7;
        #pragma unroll
        for (int j = 0; j < 4; ++j) xT[(q * 4 + j) * 40 + n] = (short)f2bf(xq[i][j]);
    }

    // ================= P2: adjacency counts (wave-local atomics) =================
    #pragma unroll
    for (int j = 0; j < 4; ++j) atomicAdd(cnts + cc_[j] * 36 + rr_[j], 1.0f);

    // ================= P3: degree + dinv (2 lanes per target row) ================
    const int c_  = l >> 1;
    const int r0_ = (l & 1) * 16;
    f32x4 cv[4];
    float s16s = 0.f;
    #pragma unroll
    for (int q = 0; q < 4; ++q) {
        cv[q] = *(const f32x4*)(cnts + c_ * 36 + r0_ + q * 4);
        s16s += cv[q][0] + cv[q][1] + cv[q][2] + cv[q][3];
    }
    float degs = s16s + __shfl_xor(s16s, 1, 64);
    float dc = rsqrtf(1.0f + degs);
    if (!(l & 1)) sdinv[c_] = dc;

    // ================= P4: normalize -> Ah bf16, rowsum ==========================
    {
        f32x4 dv[4];
        #pragma unroll
        for (int q = 0; q < 4; ++q) dv[q] = *(const f32x4*)(sdinv + r0_ + q * 4);
        float dot = 0.f;
        s16x8 o0, o1;
        #pragma unroll
        for (int k = 0; k < 16; ++k) {
            float u = cv[k >> 2][k & 3] * dv[k >> 2][k & 3];
            dot += u;
            float v = u * dc;
            if (r0_ + k == c_) v += dc * dc;
            if (k < 8) o0[k] = (short)f2bf(v); else o1[k - 8] = (short)f2bf(v);
        }
        dot += __shfl_xor(dot, 1, 64);
        if (!(l & 1)) srsum[c_] = dc * dot + dc * dc;
        *(s16x8*)(Ah + c_ * 40 + r0_)     = o0;
        *(s16x8*)(Ah + c_ * 40 + r0_ + 8) = o1;
    }

    // ================= P5: yT = xT @ AhatT (4 MFMA) -> yB[node][feat] ============
    {
        s16x8 Ax0 = *(const s16x8*)(xT + col * 40 + lg * 8);
        s16x8 Ax1 = *(const s16x8*)(xT + (16 + col) * 40 + lg * 8);
        s16x8 Af0 = *(const s16x8*)(Ah + col * 40 + lg * 8);
        s16x8 Af1 = *(const s16x8*)(Ah + (16 + col) * 40 + lg * 8);
        f32x4 y00 = {}, y01 = {}, y10 = {}, y11 = {};
        y00 = MFMA16(Ax0, Af0, y00);
        y01 = MFMA16(Ax0, Af1, y01);
        y10 = MFMA16(Ax1, Af0, y10);
        y11 = MFMA16(Ax1, Af1, y11);
        #pragma unroll
        for (int f = 0; f < 2; ++f)
            #pragma unroll
            for (int d = 0; d < 2; ++d) {
                f32x4 a = (f == 0) ? (d == 0 ? y00 : y01) : (d == 0 ? y10 : y11);
                s16x4 pk;
                pk[0] = (short)f2bf(a[0]); pk[1] = (short)f2bf(a[1]);
                pk[2] = (short)f2bf(a[2]); pk[3] = (short)f2bf(a[3]);
                *(s16x4*)(yB + (d * 16 + col) * 40 + f * 16 + lg * 4) = pk;
            }
    }

    // ================= P6: aggT = WcT @ yT (8 MFMA) -> aggB swz ==================
    {
        s16x8 Aw[4];
        #pragma unroll
        for (int a = 0; a < 4; ++a)
            Aw[a] = *(const s16x8*)(WcTB + (a * 16 + col) * 32 + lg * 8);
        s16x8 By0 = *(const s16x8*)(yB + col * 40 + lg * 8);
        s16x8 By1 = *(const s16x8*)(yB + (16 + col) * 40 + lg * 8);
        float rs0 = srsum[col], rs1 = srsum[16 + col];
        #pragma unroll
        for (int a = 0; a < 4; ++a) {
            f32x4 g0 = {}, g1 = {};
            g0 = MFMA16(Aw[a], By0, g0);
            g1 = MFMA16(Aw[a], By1, g1);
            f32x4 bc4 = *(const f32x4*)(bcw + a * 16 + lg * 4);
            f32x4 bg4 = *(const f32x4*)(b_gcn + a * 16 + lg * 4);
            #pragma unroll
            for (int n = 0; n < 2; ++n) {
                f32x4 g = n ? g1 : g0;
                float rs = n ? rs1 : rs0;
                int node = n * 16 + col;
                s16x4 pk;
                #pragma unroll
                for (int r = 0; r < 4; ++r) pk[r] = (short)f2bf(g[r] + rs * bc4[r] + bg4[r]);
                *(s16x4*)(aggB + node * 128 + ((a * 32 + lg * 8) ^ ((node & 7) << 4))) = pk;
            }
        }
    }

    // ================= P7: GRU, 12 pipelined weight clusters =====================
    s16x8 Ba[4];
    #pragma unroll
    for (int kt = 0; kt < 2; ++kt)
        #pragma unroll
        for (int nt = 0; nt < 2; ++nt) {
            int node = nt * 16 + col;
            Ba[kt * 2 + nt] = *(const s16x8*)(aggB + node * 128 +
                                              ((kt * 64 + lg * 16) ^ ((node & 7) << 4)));
        }

    float vsum = 0.f;
    s16x8 W0[4], W1[4];                   // ping-pong weight buffers
    #pragma unroll
    for (int j = 0; j < 4; ++j) {         // preload cluster c=0 (dt=0,g=0)
        const short* base = (j < 2) ? WihB : WhhB;
        W0[j] = *(const s16x8*)(base + (0 * 64 + 0 * 16 + col) * 64 + (j & 1) * 32 + lg * 8);
    }

    f32x4 ar[2] = {}, az[2] = {}, ain[2] = {}, ahn[2] = {};
    f32x4 h0p0 = {}, h0p1 = {}, br = {}, bz = {}, bin = {}, bhn = {};

    #pragma unroll
    for (int c = 0; c < 12; ++c) {        // c = dt*3 + g
        const int dt = c / 3, g = c % 3;
        const int db = dt * 16 + lg * 4;

        // prefetch next cluster's weights (issued under this cluster's MFMAs)
        if (c < 11) {
            const int gn = (g + 1) % 3, dtn = dt + (g == 2);
            #pragma unroll
            for (int j = 0; j < 4; ++j) {
                const short* base = (j < 2) ? WihB : WhhB;
                s16x8 v = *(const s16x8*)(base + (gn * 64 + dtn * 16 + col) * 64 +
                                          (j & 1) * 32 + lg * 8);
                if (c & 1) W0[j] = v; else W1[j] = v;
            }
        }
        if (g == 0) {                     // per-dt epilogue prefetch + acc reset
            h0p0 = *(const f32x4*)(h0e + col * 64 + db);
            h0p1 = *(const f32x4*)(h0e + (16 + col) * 64 + db);
            br   = *(const f32x4*)(b_ih + db);
            bz   = *(const f32x4*)(b_ih + 64 + db);
            bin  = *(const f32x4*)(b_ih + 128 + db);
            bhn  = *(const f32x4*)(b_hh + 128 + db);
            f32x4 t1 = *(const f32x4*)(b_hh + db);
            f32x4 t2 = *(const f32x4*)(b_hh + 64 + db);
            br += t1; bz += t2;
            #pragma unroll
            for (int n = 0; n < 2; ++n) {
                ar[n] = (f32x4){0.f, 0.f, 0.f, 0.f};
                az[n] = (f32x4){0.f, 0.f, 0.f, 0.f};
                ain[n] = (f32x4){0.f, 0.f, 0.f, 0.f};
                ahn[n] = (f32x4){0.f, 0.f, 0.f, 0.f};
            }
        }

        __builtin_amdgcn_s_setprio(1);
        #pragma unroll
        for (int nt = 0; nt < 2; ++nt) {
            s16x8 Wi0 = (c & 1) ? W1[0] : W0[0];
            s16x8 Wi1 = (c & 1) ? W1[1] : W0[1];
            s16x8 Wh0 = (c & 1) ? W1[2] : W0[2];
            s16x8 Wh1 = (c & 1) ? W1[3] : W0[3];
            if (g == 0) {
                ar[nt] = MFMA16(Wi0, Ba[nt], ar[nt]);
                ar[nt] = MFMA16(Wi1, Ba[2 + nt], ar[nt]);
                ar[nt] = MFMA16(Wh0, Hb[nt], ar[nt]);
                ar[nt] = MFMA16(Wh1, Hb[2 + nt], ar[nt]);
            } else if (g == 1) {
                az[nt] = MFMA16(Wi0, Ba[nt], az[nt]);
                az[nt] = MFMA16(Wi1, Ba[2 + nt], az[nt]);
                az[nt] = MFMA16(Wh0, Hb[nt], az[nt]);
                az[nt] = MFMA16(Wh1, Hb[2 + nt], az[nt]);
            } else {
                ain[nt] = MFMA16(Wi0, Ba[nt], ain[nt]);
                ain[nt] = MFMA16(Wi1, Ba[2 + nt], ain[nt]);
                ahn[nt] = MFMA16(Wh0, Hb[nt], ahn[nt]);
                ahn[nt] = MFMA16(Wh1, Hb[2 + nt], ahn[nt]);
            }
        }
        __builtin_amdgcn_s_setprio(0);

        if (g == 2) {                     // epilogue for this dt -> hnew in LDS
            #pragma unroll
            for (int nt = 0; nt < 2; ++nt) {
                int node = nt * 16 + col;
                f32x4 h04 = nt ? h0p1 : h0p0;
                f32x4 out;
                #pragma unroll
                for (int r = 0; r < 4; ++r) {
                    float rg = sigm(ar[nt][r] + br[r]);
                    float zg = sigm(az[nt][r] + bz[r]);
                    float e2 = __expf(2.f * (ain[nt][r] + bin[r] + rg * (ahn[nt][r] + bhn[r])));
                    float ng = 1.f - 2.f / (e2 + 1.f);
                    out[r] = (1.f - zg) * ng + zg * h04[r];
                }
                *(f32x4*)(eb + node * 272 + db * 4) = out;   // hnew stride 68 f32
            }
        }
    }

    // ================= P8: coalesced flush + fused value head ====================
    {
        float* ho = hid_out + (size_t)env * 2048;
        #pragma unroll
        for (int i = 0; i < 8; ++i) {
            int idx4 = l + i * 64;
            int node = idx4 >> 4, q = idx4 & 15;
            f32x4 hv = *(const f32x4*)(eb + node * 272 + q * 16);
            ((f32x4*)ho)[idx4] = hv;
            f32x4 wv = ((const f32x4*)W_out)[idx4];
            vsum += hv[0] * wv[0] + hv[1] * wv[1] + hv[2] * wv[2] + hv[3] * wv[3];
        }
        #pragma unroll
        for (int off = 32; off > 0; off >>= 1) vsum += __shfl_down(vsum, off, 64);
        if (l == 0) value[env] = vsum + b_out[0];
    }
}

// ---------------------------------------------------------------------------------
extern "C" void kernel_launch(void* const* d_in, const int* in_sizes, int n_in,
                              void* d_out, int out_size, void* d_ws, size_t ws_size,
                              hipStream_t stream)
{
    const float* x     = (const float*)d_in[0];
    const void*  edge  = d_in[1];
    const float* h0    = (const float*)d_in[2];
    const float* W_pre = (const float*)d_in[3];
    const float* b_pre = (const float*)d_in[4];
    const float* W_gcn = (const float*)d_in[5];
    const float* b_gcn = (const float*)d_in[6];
    const float* W_ih  = (const float*)d_in[7];
    const float* W_hh  = (const float*)d_in[8];
    const float* b_ih  = (const float*)d_in[9];
    const float* b_hh  = (const float*)d_in[10];
    const float* W_out = (const float*)d_in[11];
    const float* b_out = (const float*)d_in[12];

    float* value = (float*)d_out;
    float* hid   = (float*)d_out + NENV;

    short* WcTB = (short*)d_ws;                          // 2048 bf16
    float* bcw  = (float*)((char*)d_ws + 4096);          // 64 f32
    short* WihB = (short*)((char*)d_ws + 4608);          // 12288 bf16
    short* WhhB = WihB + RD3 * GD;                       // 12288 bf16

    prep_kernel<<<97, 256, 0, stream>>>(W_pre, b_pre, W_gcn, W_ih, W_hh,
                                        WcTB, bcw, WihB, WhhB);
    fused_kernel<<<NENV / 4, 256, 0, stream>>>(x, edge, h0, bcw, b_gcn, WcTB,
                                               WihB, WhhB, b_ih, b_hh,
                                               W_out, b_out, value, hid);
}

// Round 8
// 62.633 us; speedup vs baseline: 1.0551x; 1.0281x over previous
//
#include <hip/hip_runtime.h>

constexpr int NENV = 4096;
constexpr int GD   = 64;
constexpr int RD3  = 192;

typedef __attribute__((ext_vector_type(8))) short s16x8;
typedef __attribute__((ext_vector_type(4))) short s16x4;
typedef __attribute__((ext_vector_type(4))) float f32x4;

__device__ __forceinline__ unsigned short f2bf(float f) {
    unsigned u = __float_as_uint(f);
    u += 0x7FFFu + ((u >> 16) & 1u);
    return (unsigned short)(u >> 16);
}
__device__ __forceinline__ float sigm(float v) { return 1.f / (1.f + __expf(-v)); }

__device__ __forceinline__ s16x8 cvt8(const float* p) {
    f32x4 a = *(const f32x4*)p;
    f32x4 b = *(const f32x4*)(p + 4);
    s16x8 r;
    r[0] = (short)f2bf(a[0]); r[1] = (short)f2bf(a[1]);
    r[2] = (short)f2bf(a[2]); r[3] = (short)f2bf(a[3]);
    r[4] = (short)f2bf(b[0]); r[5] = (short)f2bf(b[1]);
    r[6] = (short)f2bf(b[2]); r[7] = (short)f2bf(b[3]);
    return r;
}

#define MFMA16(A, B, C) __builtin_amdgcn_mfma_f32_16x16x32_bf16(A, B, C, 0, 0, 0)

// ---- K0: blocks 0..95 cvt W_ih/W_hh -> bf16; block 96 folds Wc^T (bf16) + bc ----
__global__ __launch_bounds__(256) void prep_kernel(
    const float* __restrict__ W_pre, const float* __restrict__ b_pre,
    const float* __restrict__ W_gcn,
    const float* __restrict__ W_ih,  const float* __restrict__ W_hh,
    short* __restrict__ WcTB, float* __restrict__ bcw,
    short* __restrict__ WihB, short* __restrict__ WhhB)
{
    int b = blockIdx.x, t = threadIdx.x;
    if (b == 96) {
        for (int o = t; o < 32 * GD; o += 256) {
            int k = o >> 6, d = o & 63;
            float s = 0.f;
            for (int m = 0; m < GD; ++m) s += W_pre[k * GD + m] * W_gcn[m * GD + d];
            WcTB[d * 32 + k] = (short)f2bf(s);
        }
        if (t < GD) {
            float s = 0.f;
            for (int m = 0; m < GD; ++m) s += b_pre[m] * W_gcn[m * GD + t];
            bcw[t] = s;
        }
    } else {
        int i = b * 256 + t;
        if (i < RD3 * GD) WihB[i] = (short)f2bf(W_ih[i]);
        else              WhhB[i - RD3 * GD] = (short)f2bf(W_hh[i - RD3 * GD]);
    }
}

// ==== K1: GCN only. 4 independent waves/block, wave = env, zero barriers. ========
// Output: agg bf16 packed into the LOW 128B of each node's 256B hid slot.
__global__ __launch_bounds__(256, 4) void gcn_kernel(
    const float* __restrict__ x,      // [4096][32][32]
    const void*  __restrict__ edge,   // [4096][2][256] int32 or int64
    const float* __restrict__ bcw,    // [64]
    const float* __restrict__ b_gcn,  // [64]
    const short* __restrict__ WcTB,   // [64][32] bf16
    float* __restrict__ hid)          // [N][64] f32 region (agg staging target)
{
    __shared__ __align__(16) char smem[39936];

    const int t   = threadIdx.x;
    const int w   = t >> 6;
    const int l   = t & 63;
    const int col = l & 15, lg = l >> 4;
    const int env = blockIdx.x * 4 + w;

    char*  eb    = smem + w * 9984;
    float* cnts  = (float*)eb;
    short* yB    = (short*)eb;
    short* xT    = (short*)(eb + 4608);
    short* Ah    = (short*)(eb + 7168);
    float* sdinv = (float*)(eb + 9728);
    float* srsum = (float*)(eb + 9856);

    // ---- P0: loads ----
    const int4* pg = (const int4*)edge;   // dtype probe (first 2KB)
    int4 pa = pg[l], pb = pg[l + 64];
    f32x4 xq[4];
    #pragma unroll
    for (int i = 0; i < 4; ++i) xq[i] = ((const f32x4*)(x + (size_t)env * 1024))[l + i * 64];

    const bool is32 = (__any((pa.y | pa.w | pb.y | pb.w) != 0) != 0);
    int rr_[4], cc_[4];
    if (is32) {
        const int4* e4 = (const int4*)((const char*)edge + (size_t)env * 2048);
        int4 r4 = e4[l], c4 = e4[64 + l];
        rr_[0] = r4.x; rr_[1] = r4.y; rr_[2] = r4.z; rr_[3] = r4.w;
        cc_[0] = c4.x; cc_[1] = c4.y; cc_[2] = c4.z; cc_[3] = c4.w;
    } else {
        const int4* e4 = (const int4*)((const char*)edge + (size_t)env * 4096);
        int4 ra = e4[2 * l], rb = e4[2 * l + 1];
        int4 ca = e4[128 + 2 * l], cb = e4[128 + 2 * l + 1];
        rr_[0] = ra.x; rr_[1] = ra.z; rr_[2] = rb.x; rr_[3] = rb.z;
        cc_[0] = ca.x; cc_[1] = ca.z; cc_[2] = cb.x; cc_[3] = cb.z;
    }

    // ---- P1: zero counts, stage xT ----
    #pragma unroll
    for (int i = 0; i < 5; ++i) {
        int o = l + i * 64;
        if (o < 288) ((f32x4*)cnts)[o] = (f32x4){0.f, 0.f, 0.f, 0.f};
    }
    #pragma unroll
    for (int i = 0; i < 4; ++i) {
        int idx4 = l + i * 64;
        int n = idx4 >> 3, q = idx4 & 7;
        #pragma unroll
        for (int j = 0; j < 4; ++j) xT[(q * 4 + j) * 40 + n] = (short)f2bf(xq[i][j]);
    }

    // ---- P2: adjacency counts ----
    #pragma unroll
    for (int j = 0; j < 4; ++j) atomicAdd(cnts + cc_[j] * 36 + rr_[j], 1.0f);

    // ---- P3: degree + dinv ----
    const int c_  = l >> 1;
    const int r0_ = (l & 1) * 16;
    f32x4 cv[4];
    float s16s = 0.f;
    #pragma unroll
    for (int q = 0; q < 4; ++q) {
        cv[q] = *(const f32x4*)(cnts + c_ * 36 + r0_ + q * 4);
        s16s += cv[q][0] + cv[q][1] + cv[q][2] + cv[q][3];
    }
    float degs = s16s + __shfl_xor(s16s, 1, 64);
    float dc = rsqrtf(1.0f + degs);
    if (!(l & 1)) sdinv[c_] = dc;

    // ---- P4: normalize -> Ah bf16, rowsum ----
    {
        f32x4 dv[4];
        #pragma unroll
        for (int q = 0; q < 4; ++q) dv[q] = *(const f32x4*)(sdinv + r0_ + q * 4);
        float dot = 0.f;
        s16x8 o0, o1;
        #pragma unroll
        for (int k = 0; k < 16; ++k) {
            float u = cv[k >> 2][k & 3] * dv[k >> 2][k & 3];
            dot += u;
            float v = u * dc;
            if (r0_ + k == c_) v += dc * dc;
            if (k < 8) o0[k] = (short)f2bf(v); else o1[k - 8] = (short)f2bf(v);
        }
        dot += __shfl_xor(dot, 1, 64);
        if (!(l & 1)) srsum[c_] = dc * dot + dc * dc;
        *(s16x8*)(Ah + c_ * 40 + r0_)     = o0;
        *(s16x8*)(Ah + c_ * 40 + r0_ + 8) = o1;
    }

    // ---- P5: yT = xT @ AhatT (4 MFMA) ----
    {
        s16x8 Ax0 = *(const s16x8*)(xT + col * 40 + lg * 8);
        s16x8 Ax1 = *(const s16x8*)(xT + (16 + col) * 40 + lg * 8);
        s16x8 Af0 = *(const s16x8*)(Ah + col * 40 + lg * 8);
        s16x8 Af1 = *(const s16x8*)(Ah + (16 + col) * 40 + lg * 8);
        f32x4 y00 = {}, y01 = {}, y10 = {}, y11 = {};
        y00 = MFMA16(Ax0, Af0, y00);
        y01 = MFMA16(Ax0, Af1, y01);
        y10 = MFMA16(Ax1, Af0, y10);
        y11 = MFMA16(Ax1, Af1, y11);
        #pragma unroll
        for (int f = 0; f < 2; ++f)
            #pragma unroll
            for (int d = 0; d < 2; ++d) {
                f32x4 a = (f == 0) ? (d == 0 ? y00 : y01) : (d == 0 ? y10 : y11);
                s16x4 pk;
                pk[0] = (short)f2bf(a[0]); pk[1] = (short)f2bf(a[1]);
                pk[2] = (short)f2bf(a[2]); pk[3] = (short)f2bf(a[3]);
                *(s16x4*)(yB + (d * 16 + col) * 40 + f * 16 + lg * 4) = pk;
            }
    }

    // ---- P6: aggT = WcT @ yT (8 MFMA) -> agg bf16 to global (low half of slot) --
    {
        s16x8 Aw[4];
        #pragma unroll
        for (int a = 0; a < 4; ++a)
            Aw[a] = *(const s16x8*)(WcTB + (a * 16 + col) * 32 + lg * 8);
        s16x8 By0 = *(const s16x8*)(yB + col * 40 + lg * 8);
        s16x8 By1 = *(const s16x8*)(yB + (16 + col) * 40 + lg * 8);
        float rs0 = srsum[col], rs1 = srsum[16 + col];
        char* agout = (char*)hid + (size_t)env * 32 * 256;
        #pragma unroll
        for (int a = 0; a < 4; ++a) {
            f32x4 g0 = {}, g1 = {};
            g0 = MFMA16(Aw[a], By0, g0);
            g1 = MFMA16(Aw[a], By1, g1);
            f32x4 bc4 = *(const f32x4*)(bcw + a * 16 + lg * 4);
            f32x4 bg4 = *(const f32x4*)(b_gcn + a * 16 + lg * 4);
            #pragma unroll
            for (int n = 0; n < 2; ++n) {
                f32x4 g = n ? g1 : g0;
                float rs = n ? rs1 : rs0;
                int node = n * 16 + col;
                s16x4 pk;
                #pragma unroll
                for (int r = 0; r < 4; ++r) pk[r] = (short)f2bf(g[r] + rs * bc4[r] + bg4[r]);
                *(s16x4*)(agout + node * 256 + a * 32 + lg * 8) = pk;
            }
        }
    }
}

// ==== K2: GRU + value head. Wave = env; weights staged once in LDS (swizzled). ===
__global__ __launch_bounds__(256, 3) void gru_kernel(
    const float* __restrict__ h0f,    // [N][64] f32
    const short* __restrict__ WihB,   // [192][64] bf16 (ws)
    const short* __restrict__ WhhB,   // [192][64] bf16 (ws)
    const float* __restrict__ b_ih, const float* __restrict__ b_hh,
    const float* __restrict__ W_out,  // [2048]
    const float* __restrict__ b_out,
    float* __restrict__ value,        // [4096]
    float* __restrict__ hid)          // [N][64] f32; low 128B/node = agg bf16 (in)
{
    __shared__ __align__(16) char sw[49152];   // [384 rows][128B], XOR-swizzled

    const int t = threadIdx.x, w = t >> 6, l = t & 63;
    const int col = l & 15, lg = l >> 4;
    const int env = blockIdx.x * 4 + w;

    // ---- stage weights (48KB) with st-swizzle: off ^= ((row&7)<<4) ----
    #pragma unroll
    for (int i = 0; i < 12; ++i) {
        int off = (t + i * 256) * 16;          // 0..49136, 16B chunks
        const char* src = (off < 24576) ? (const char*)WihB + off
                                        : (const char*)WhhB + (off - 24576);
        s16x8 v = *(const s16x8*)src;
        *(s16x8*)(sw + (off ^ (((off >> 7) & 7) << 4))) = v;
    }

    // ---- B-fragments: agg (bf16, direct) + h0 (f32 -> cvt), before barrier ----
    const char*  aggb = (const char*)hid + (size_t)env * 32 * 256;
    const float* h0e  = h0f + (size_t)env * 2048;
    s16x8 Ba[4], Hb[4];
    #pragma unroll
    for (int kt = 0; kt < 2; ++kt)
        #pragma unroll
        for (int nt = 0; nt < 2; ++nt) {
            int node = nt * 16 + col;
            Ba[kt * 2 + nt] = *(const s16x8*)(aggb + node * 256 + kt * 64 + lg * 16);
            Hb[kt * 2 + nt] = cvt8(h0e + node * 64 + kt * 32 + lg * 8);
        }
    __syncthreads();

    // weight fragment fetch: rows row&7 == col&7 -> 2-way bank alias (free)
    auto WF = [&](int hh, int g3, int gd, int kt) -> s16x8 {
        int row = g3 * 64 + gd * 16 + col;
        int off = hh * 24576 + row * 128 + kt * 64 + lg * 16;
        return *(const s16x8*)(sw + (off ^ ((row & 7) << 4)));
    };

    float vsum = 0.f;
    #pragma unroll
    for (int gd = 0; gd < 4; ++gd) {
        const int db = gd * 16 + lg * 4;
        // epilogue operand prefetch (L1/L2-hot)
        f32x4 h0p[2], wvp[2];
        #pragma unroll
        for (int nt = 0; nt < 2; ++nt) {
            h0p[nt] = *(const f32x4*)(h0e + (nt * 16 + col) * 64 + db);
            wvp[nt] = *(const f32x4*)(W_out + (nt * 16 + col) * 64 + db);
        }
        f32x4 br  = *(const f32x4*)(b_ih + db);
        f32x4 bz  = *(const f32x4*)(b_ih + 64 + db);
        f32x4 bin = *(const f32x4*)(b_ih + 128 + db);
        f32x4 bhn = *(const f32x4*)(b_hh + 128 + db);
        {
            f32x4 t1 = *(const f32x4*)(b_hh + db);
            f32x4 t2 = *(const f32x4*)(b_hh + 64 + db);
            br += t1; bz += t2;
        }

        f32x4 ar[2] = {}, az[2] = {}, ain[2] = {}, ahn[2] = {};
        __builtin_amdgcn_s_setprio(1);
        #pragma unroll
        for (int kt = 0; kt < 2; ++kt) {
            s16x8 Wri = WF(0, 0, gd, kt), Wrh = WF(1, 0, gd, kt);
            s16x8 Wzi = WF(0, 1, gd, kt), Wzh = WF(1, 1, gd, kt);
            s16x8 Wni = WF(0, 2, gd, kt), Wnh = WF(1, 2, gd, kt);
            #pragma unroll
            for (int nt = 0; nt < 2; ++nt) {
                ar[nt]  = MFMA16(Wri, Ba[kt * 2 + nt], ar[nt]);
                ar[nt]  = MFMA16(Wrh, Hb[kt * 2 + nt], ar[nt]);
                az[nt]  = MFMA16(Wzi, Ba[kt * 2 + nt], az[nt]);
                az[nt]  = MFMA16(Wzh, Hb[kt * 2 + nt], az[nt]);
                ain[nt] = MFMA16(Wni, Ba[kt * 2 + nt], ain[nt]);
                ahn[nt] = MFMA16(Wnh, Hb[kt * 2 + nt], ahn[nt]);
            }
        }
        __builtin_amdgcn_s_setprio(0);

        // epilogue: hnew -> hid (direct), value partial in-register
        #pragma unroll
        for (int nt = 0; nt < 2; ++nt) {
            int node = nt * 16 + col;
            f32x4 out;
            #pragma unroll
            for (int r = 0; r < 4; ++r) {
                float rg = sigm(ar[nt][r] + br[r]);
                float zg = sigm(az[nt][r] + bz[r]);
                float e2 = __expf(2.f * (ain[nt][r] + bin[r] + rg * (ahn[nt][r] + bhn[r])));
                float ng = 1.f - 2.f / (e2 + 1.f);
                out[r] = (1.f - zg) * ng + zg * h0p[nt][r];
            }
            *(f32x4*)(hid + (size_t)env * 2048 + node * 64 + db) = out;
            f32x4 wv = wvp[nt];
            vsum += out[0] * wv[0] + out[1] * wv[1] + out[2] * wv[2] + out[3] * wv[3];
        }
    }

    // ---- value reduce (single env per wave) ----
    #pragma unroll
    for (int off = 32; off > 0; off >>= 1) vsum += __shfl_down(vsum, off, 64);
    if (l == 0) value[env] = vsum + b_out[0];
}

// ---------------------------------------------------------------------------------
extern "C" void kernel_launch(void* const* d_in, const int* in_sizes, int n_in,
                              void* d_out, int out_size, void* d_ws, size_t ws_size,
                              hipStream_t stream)
{
    const float* x     = (const float*)d_in[0];
    const void*  edge  = d_in[1];
    const float* h0    = (const float*)d_in[2];
    const float* W_pre = (const float*)d_in[3];
    const float* b_pre = (const float*)d_in[4];
    const float* W_gcn = (const float*)d_in[5];
    const float* b_gcn = (const float*)d_in[6];
    const float* W_ih  = (const float*)d_in[7];
    const float* W_hh  = (const float*)d_in[8];
    const float* b_ih  = (const float*)d_in[9];
    const float* b_hh  = (const float*)d_in[10];
    const float* W_out = (const float*)d_in[11];
    const float* b_out = (const float*)d_in[12];

    float* value = (float*)d_out;
    float* hid   = (float*)d_out + NENV;

    short* WcTB = (short*)d_ws;                          // 2048 bf16
    float* bcw  = (float*)((char*)d_ws + 4096);          // 64 f32
    short* WihB = (short*)((char*)d_ws + 4608);          // 12288 bf16
    short* WhhB = WihB + RD3 * GD;                       // 12288 bf16

    prep_kernel<<<97, 256, 0, stream>>>(W_pre, b_pre, W_gcn, W_ih, W_hh,
                                        WcTB, bcw, WihB, WhhB);
    gcn_kernel<<<NENV / 4, 256, 0, stream>>>(x, edge, bcw, b_gcn, WcTB, hid);
    gru_kernel<<<NENV / 4, 256, 0, stream>>>(h0, WihB, WhhB, b_ih, b_hh,
                                             W_out, b_out, value, hid);
}

// Round 10
// 62.101 us; speedup vs baseline: 1.0641x; 1.0086x over previous
//
#include <hip/hip_runtime.h>

constexpr int NENV = 4096;
constexpr int GD   = 64;
constexpr int RD3  = 192;

typedef __attribute__((ext_vector_type(8))) short s16x8;
typedef __attribute__((ext_vector_type(4))) short s16x4;
typedef __attribute__((ext_vector_type(4))) float f32x4;

__device__ __forceinline__ unsigned short f2bf(float f) {
    unsigned u = __float_as_uint(f);
    u += 0x7FFFu + ((u >> 16) & 1u);
    return (unsigned short)(u >> 16);
}
__device__ __forceinline__ float bf2f(unsigned short u) {
    return __uint_as_float((unsigned)u << 16);
}
__device__ __forceinline__ float sigm(float v) { return 1.f / (1.f + __expf(-v)); }

#define MFMA16(A, B, C) __builtin_amdgcn_mfma_f32_16x16x32_bf16(A, B, C, 0, 0, 0)

// ---- K0: blocks 0..95 cvt W_ih/W_hh -> bf16; block 96 folds Wc^T (bf16) + bc ----
__global__ __launch_bounds__(256) void prep_kernel(
    const float* __restrict__ W_pre, const float* __restrict__ b_pre,
    const float* __restrict__ W_gcn,
    const float* __restrict__ W_ih,  const float* __restrict__ W_hh,
    short* __restrict__ WcTB, float* __restrict__ bcw,
    short* __restrict__ WihB, short* __restrict__ WhhB)
{
    int b = blockIdx.x, t = threadIdx.x;
    if (b == 96) {
        for (int o = t; o < 32 * GD; o += 256) {
            int k = o >> 6, d = o & 63;
            float s = 0.f;
            for (int m = 0; m < GD; ++m) s += W_pre[k * GD + m] * W_gcn[m * GD + d];
            WcTB[d * 32 + k] = (short)f2bf(s);
        }
        if (t < GD) {
            float s = 0.f;
            for (int m = 0; m < GD; ++m) s += b_pre[m] * W_gcn[m * GD + t];
            bcw[t] = s;
        }
    } else {
        int i = b * 256 + t;
        if (i < RD3 * GD) WihB[i] = (short)f2bf(W_ih[i]);
        else              WhhB[i - RD3 * GD] = (short)f2bf(W_hh[i - RD3 * GD]);
    }
}

// ==== K1: GCN. 4 independent waves/block, wave = env, zero barriers. =============
// agg -> LDS (swizzled bf16 [32 rows][128B]) -> LINEAR byte flush (4KB/env) into
// the first 4KB of each env's 8KB hid slot. All global I/O coalesced.
__global__ __launch_bounds__(256, 4) void gcn_kernel(
    const float* __restrict__ x,      // [4096][32][32]
    const void*  __restrict__ edge,   // [4096][2][256] int32 or int64
    const float* __restrict__ bcw,    // [64]
    const float* __restrict__ b_gcn,  // [64]
    const short* __restrict__ WcTB,   // [64][32] bf16
    float* __restrict__ hid)          // [N][64] f32 region (agg staging target)
{
    __shared__ __align__(16) char smem[39936];

    const int t   = threadIdx.x;
    const int w   = t >> 6;
    const int l   = t & 63;
    const int col = l & 15, lg = l >> 4;
    const int env = blockIdx.x * 4 + w;

    char*  eb    = smem + w * 9984;
    float* cnts  = (float*)eb;
    short* yB    = (short*)eb;
    short* xT    = (short*)(eb + 4608);
    short* Ah    = (short*)(eb + 7168);
    char*  aggB  = eb + 4608;              // overlays dead xT/Ah after P5
    float* sdinv = (float*)(eb + 9728);
    float* srsum = (float*)(eb + 9856);

    // ---- P0: loads ----
    const int4* pg = (const int4*)edge;    // dtype probe (first 2KB)
    int4 pa = pg[l], pb = pg[l + 64];
    f32x4 xq[4];
    #pragma unroll
    for (int i = 0; i < 4; ++i) xq[i] = ((const f32x4*)(x + (size_t)env * 1024))[l + i * 64];

    const bool is32 = (__any((pa.y | pa.w | pb.y | pb.w) != 0) != 0);
    int rr_[4], cc_[4];
    if (is32) {
        const int4* e4 = (const int4*)((const char*)edge + (size_t)env * 2048);
        int4 r4 = e4[l], c4 = e4[64 + l];
        rr_[0] = r4.x; rr_[1] = r4.y; rr_[2] = r4.z; rr_[3] = r4.w;
        cc_[0] = c4.x; cc_[1] = c4.y; cc_[2] = c4.z; cc_[3] = c4.w;
    } else {
        const int4* e4 = (const int4*)((const char*)edge + (size_t)env * 4096);
        int4 ra = e4[2 * l], rb = e4[2 * l + 1];
        int4 ca = e4[128 + 2 * l], cb = e4[128 + 2 * l + 1];
        rr_[0] = ra.x; rr_[1] = ra.z; rr_[2] = rb.x; rr_[3] = rb.z;
        cc_[0] = ca.x; cc_[1] = ca.z; cc_[2] = cb.x; cc_[3] = cb.z;
    }

    // ---- P1: zero counts, stage xT ----
    #pragma unroll
    for (int i = 0; i < 5; ++i) {
        int o = l + i * 64;
        if (o < 288) ((f32x4*)cnts)[o] = (f32x4){0.f, 0.f, 0.f, 0.f};
    }
    #pragma unroll
    for (int i = 0; i < 4; ++i) {
        int idx4 = l + i * 64;
        int n = idx4 >> 3, q = idx4 & 7;
        #pragma unroll
        for (int j = 0; j < 4; ++j) xT[(q * 4 + j) * 40 + n] = (short)f2bf(xq[i][j]);
    }

    // ---- P2: adjacency counts ----
    #pragma unroll
    for (int j = 0; j < 4; ++j) atomicAdd(cnts + cc_[j] * 36 + rr_[j], 1.0f);

    // ---- P3: degree + dinv ----
    const int c_  = l >> 1;
    const int r0_ = (l & 1) * 16;
    f32x4 cv[4];
    float s16s = 0.f;
    #pragma unroll
    for (int q = 0; q < 4; ++q) {
        cv[q] = *(const f32x4*)(cnts + c_ * 36 + r0_ + q * 4);
        s16s += cv[q][0] + cv[q][1] + cv[q][2] + cv[q][3];
    }
    float degs = s16s + __shfl_xor(s16s, 1, 64);
    float dc = rsqrtf(1.0f + degs);
    if (!(l & 1)) sdinv[c_] = dc;

    // ---- P4: normalize -> Ah bf16, rowsum ----
    {
        f32x4 dv[4];
        #pragma unroll
        for (int q = 0; q < 4; ++q) dv[q] = *(const f32x4*)(sdinv + r0_ + q * 4);
        float dot = 0.f;
        s16x8 o0, o1;
        #pragma unroll
        for (int k = 0; k < 16; ++k) {
            float u = cv[k >> 2][k & 3] * dv[k >> 2][k & 3];
            dot += u;
            float v = u * dc;
            if (r0_ + k == c_) v += dc * dc;
            if (k < 8) o0[k] = (short)f2bf(v); else o1[k - 8] = (short)f2bf(v);
        }
        dot += __shfl_xor(dot, 1, 64);
        if (!(l & 1)) srsum[c_] = dc * dot + dc * dc;
        *(s16x8*)(Ah + c_ * 40 + r0_)     = o0;
        *(s16x8*)(Ah + c_ * 40 + r0_ + 8) = o1;
    }

    // ---- P5: yT = xT @ AhatT (4 MFMA) ----
    {
        s16x8 Ax0 = *(const s16x8*)(xT + col * 40 + lg * 8);
        s16x8 Ax1 = *(const s16x8*)(xT + (16 + col) * 40 + lg * 8);
        s16x8 Af0 = *(const s16x8*)(Ah + col * 40 + lg * 8);
        s16x8 Af1 = *(const s16x8*)(Ah + (16 + col) * 40 + lg * 8);
        f32x4 y00 = {}, y01 = {}, y10 = {}, y11 = {};
        y00 = MFMA16(Ax0, Af0, y00);
        y01 = MFMA16(Ax0, Af1, y01);
        y10 = MFMA16(Ax1, Af0, y10);
        y11 = MFMA16(Ax1, Af1, y11);
        #pragma unroll
        for (int f = 0; f < 2; ++f)
            #pragma unroll
            for (int d = 0; d < 2; ++d) {
                f32x4 a = (f == 0) ? (d == 0 ? y00 : y01) : (d == 0 ? y10 : y11);
                s16x4 pk;
                pk[0] = (short)f2bf(a[0]); pk[1] = (short)f2bf(a[1]);
                pk[2] = (short)f2bf(a[2]); pk[3] = (short)f2bf(a[3]);
                *(s16x4*)(yB + (d * 16 + col) * 40 + f * 16 + lg * 4) = pk;
            }
    }

    // ---- P6: aggT = WcT @ yT (8 MFMA) -> aggB (swizzled LDS) ----
    {
        s16x8 Aw[4];
        #pragma unroll
        for (int a = 0; a < 4; ++a)
            Aw[a] = *(const s16x8*)(WcTB + (a * 16 + col) * 32 + lg * 8);
        s16x8 By0 = *(const s16x8*)(yB + col * 40 + lg * 8);
        s16x8 By1 = *(const s16x8*)(yB + (16 + col) * 40 + lg * 8);
        float rs0 = srsum[col], rs1 = srsum[16 + col];
        #pragma unroll
        for (int a = 0; a < 4; ++a) {
            f32x4 g0 = {}, g1 = {};
            g0 = MFMA16(Aw[a], By0, g0);
            g1 = MFMA16(Aw[a], By1, g1);
            f32x4 bc4 = *(const f32x4*)(bcw + a * 16 + lg * 4);
            f32x4 bg4 = *(const f32x4*)(b_gcn + a * 16 + lg * 4);
            #pragma unroll
            for (int n = 0; n < 2; ++n) {
                f32x4 g = n ? g1 : g0;
                float rs = n ? rs1 : rs0;
                int node = n * 16 + col;
                s16x4 pk;
                #pragma unroll
                for (int r = 0; r < 4; ++r) pk[r] = (short)f2bf(g[r] + rs * bc4[r] + bg4[r]);
                *(s16x4*)(aggB + node * 128 + ((a * 32 + lg * 8) ^ ((node & 7) << 4))) = pk;
            }
        }
    }

    // ---- P7: LINEAR flush of pre-swizzled agg bytes (coalesced 1KB/instr) ----
    {
        char* agout = (char*)hid + (size_t)env * 8192;    // first 4KB of env slot
        #pragma unroll
        for (int i = 0; i < 4; ++i) {
            int idx = l + i * 64;                         // 0..255 x 16B
            s16x8 v = *(const s16x8*)(aggB + idx * 16);
            *(s16x8*)(agout + idx * 16) = v;
        }
    }
}

// ==== K2: GRU + value head. Block = 4 envs; ALL global I/O coalesced; ============
// fragments scattered only in LDS (swizzled). One barrier.
// LDS: [0,49152) W swz | per-env e at 49152+e*8192: [aggB 4KB | h0B 4KB],
//      hnew f32 [32][256B] (swz) aliases the whole 8KB after frag/blend preload.
__global__ __launch_bounds__(256, 2) void gru_kernel(
    const float* __restrict__ h0f,    // [N][64] f32
    const short* __restrict__ WihB,   // [192][64] bf16 (ws)
    const short* __restrict__ WhhB,   // [192][64] bf16 (ws)
    const float* __restrict__ b_ih, const float* __restrict__ b_hh,
    const float* __restrict__ W_out,  // [2048]
    const float* __restrict__ b_out,
    float* __restrict__ value,        // [4096]
    float* __restrict__ hid)          // [N][64] f32; first 4KB/env slot = swz agg
{
    __shared__ __align__(16) char smem[81920];
    char* sw = smem;

    const int t = threadIdx.x, w = t >> 6, l = t & 63;
    const int col = l & 15, lg = l >> 4;
    const int env = blockIdx.x * 4 + w;

    // ---- cooperative coalesced staging ----
    #pragma unroll
    for (int i = 0; i < 12; ++i) {                   // W 48KB, swizzled
        int off = (t + i * 256) * 16;
        const char* src = (off < 24576) ? (const char*)WihB + off
                                        : (const char*)WhhB + (off - 24576);
        s16x8 v = *(const s16x8*)src;
        *(s16x8*)(sw + (off ^ (((off >> 7) & 7) << 4))) = v;
    }
    {
        // agg: env e's 4KB lives at slot stride 8192B (first half). FIX (R9 bug):
        // read with the matching per-env slot stride, still fully coalesced
        // (for each i, all 256 lanes read one env's contiguous 4KB).
        const char* aggsrc = (const char*)hid + (size_t)blockIdx.x * 32768;
        #pragma unroll
        for (int i = 0; i < 4; ++i) {
            int idx = t + i * 256;                   // 0..1023 16B chunks
            int e = idx >> 8, q = idx & 255;
            s16x8 v = *(const s16x8*)(aggsrc + e * 8192 + q * 16);
            *(s16x8*)(smem + 49152 + e * 8192 + q * 16) = v;
        }
        const float* h0src = h0f + (size_t)blockIdx.x * 8192;
        #pragma unroll
        for (int i = 0; i < 8; ++i) {                // h0 f32 -> bf16 swz LDS
            int idx = t + i * 256;                   // 0..2047 f32x4 chunks
            f32x4 hv = *(const f32x4*)(h0src + idx * 4);
            s16x4 pk;
            pk[0] = (short)f2bf(hv[0]); pk[1] = (short)f2bf(hv[1]);
            pk[2] = (short)f2bf(hv[2]); pk[3] = (short)f2bf(hv[3]);
            int e = idx >> 9, off = (idx & 511) * 8;
            int row = off >> 7, rb = off & 127;
            *(s16x4*)(smem + 49152 + e * 8192 + 4096 + row * 128 +
                      (rb ^ ((row & 7) << 4))) = pk;
        }
    }
    __syncthreads();

    char* eb  = smem + 49152 + w * 8192;
    char* agg = eb;
    char* h0b = eb + 4096;

    // ---- preload ALL LDS-sourced values (before hnew overwrites the region) ----
    s16x8 Ba[4], Hb[4];
    #pragma unroll
    for (int kt = 0; kt < 2; ++kt)
        #pragma unroll
        for (int nt = 0; nt < 2; ++nt) {
            int node = nt * 16 + col;
            int o = node * 128 + ((kt * 64 + lg * 16) ^ ((node & 7) << 4));
            Ba[kt * 2 + nt] = *(const s16x8*)(agg + o);
            Hb[kt * 2 + nt] = *(const s16x8*)(h0b + o);
        }
    s16x4 hbl[8];                                    // blend h0 [gd][nt]
    #pragma unroll
    for (int gd = 0; gd < 4; ++gd)
        #pragma unroll
        for (int nt = 0; nt < 2; ++nt) {
            int node = nt * 16 + col;
            hbl[gd * 2 + nt] = *(const s16x4*)(h0b + node * 128 +
                                 ((gd * 32 + lg * 8) ^ ((node & 7) << 4)));
        }

    // weight fragment fetch (swizzled, 2-way max)
    auto WF = [&](int hh, int g3, int gd, int kt) -> s16x8 {
        int row = g3 * 64 + gd * 16 + col;
        int off = hh * 24576 + row * 128 + kt * 64 + lg * 16;
        return *(const s16x8*)(sw + (off ^ ((row & 7) << 4)));
    };

    // ---- GRU per d-tile; hnew -> swizzled LDS ----
    #pragma unroll
    for (int gd = 0; gd < 4; ++gd) {
        const int db = gd * 16 + lg * 4;
        f32x4 br  = *(const f32x4*)(b_ih + db);
        f32x4 bz  = *(const f32x4*)(b_ih + 64 + db);
        f32x4 bin = *(const f32x4*)(b_ih + 128 + db);
        f32x4 bhn = *(const f32x4*)(b_hh + 128 + db);
        {
            f32x4 t1 = *(const f32x4*)(b_hh + db);
            f32x4 t2 = *(const f32x4*)(b_hh + 64 + db);
            br += t1; bz += t2;
        }

        f32x4 ar[2] = {}, az[2] = {}, ain[2] = {}, ahn[2] = {};
        __builtin_amdgcn_s_setprio(1);
        #pragma unroll
        for (int kt = 0; kt < 2; ++kt) {
            s16x8 Wri = WF(0, 0, gd, kt), Wrh = WF(1, 0, gd, kt);
            s16x8 Wzi = WF(0, 1, gd, kt), Wzh = WF(1, 1, gd, kt);
            s16x8 Wni = WF(0, 2, gd, kt), Wnh = WF(1, 2, gd, kt);
            #pragma unroll
            for (int nt = 0; nt < 2; ++nt) {
                ar[nt]  = MFMA16(Wri, Ba[kt * 2 + nt], ar[nt]);
                ar[nt]  = MFMA16(Wrh, Hb[kt * 2 + nt], ar[nt]);
                az[nt]  = MFMA16(Wzi, Ba[kt * 2 + nt], az[nt]);
                az[nt]  = MFMA16(Wzh, Hb[kt * 2 + nt], az[nt]);
                ain[nt] = MFMA16(Wni, Ba[kt * 2 + nt], ain[nt]);
                ahn[nt] = MFMA16(Wnh, Hb[kt * 2 + nt], ahn[nt]);
            }
        }
        __builtin_amdgcn_s_setprio(0);

        #pragma unroll
        for (int nt = 0; nt < 2; ++nt) {
            int node = nt * 16 + col;
            s16x4 h04 = hbl[gd * 2 + nt];
            f32x4 out;
            #pragma unroll
            for (int r = 0; r < 4; ++r) {
                float rg = sigm(ar[nt][r] + br[r]);
                float zg = sigm(az[nt][r] + bz[r]);
                float e2 = __expf(2.f * (ain[nt][r] + bin[r] + rg * (ahn[nt][r] + bhn[r])));
                float ng = 1.f - 2.f / (e2 + 1.f);
                out[r] = (1.f - zg) * ng + zg * bf2f((unsigned short)h04[r]);
            }
            *(f32x4*)(eb + node * 256 + ((db * 4) ^ ((node & 7) << 4))) = out;
        }
    }

    // ---- coalesced flush (1KB/instr) + fused value head (linear W_out) ----
    {
        float* ho = hid + (size_t)env * 2048;
        float vsum = 0.f;
        #pragma unroll
        for (int i = 0; i < 8; ++i) {
            int idx4 = l + i * 64;                   // 0..511
            int node = idx4 >> 4, q = idx4 & 15;
            f32x4 hv = *(const f32x4*)(eb + node * 256 + ((q * 16) ^ ((node & 7) << 4)));
            ((f32x4*)ho)[idx4] = hv;
            f32x4 wv = ((const f32x4*)W_out)[idx4];
            vsum += hv[0] * wv[0] + hv[1] * wv[1] + hv[2] * wv[2] + hv[3] * wv[3];
        }
        #pragma unroll
        for (int off = 32; off > 0; off >>= 1) vsum += __shfl_down(vsum, off, 64);
        if (l == 0) value[env] = vsum + b_out[0];
    }
}

// ---------------------------------------------------------------------------------
extern "C" void kernel_launch(void* const* d_in, const int* in_sizes, int n_in,
                              void* d_out, int out_size, void* d_ws, size_t ws_size,
                              hipStream_t stream)
{
    const float* x     = (const float*)d_in[0];
    const void*  edge  = d_in[1];
    const float* h0    = (const float*)d_in[2];
    const float* W_pre = (const float*)d_in[3];
    const float* b_pre = (const float*)d_in[4];
    const float* W_gcn = (const float*)d_in[5];
    const float* b_gcn = (const float*)d_in[6];
    const float* W_ih  = (const float*)d_in[7];
    const float* W_hh  = (const float*)d_in[8];
    const float* b_ih  = (const float*)d_in[9];
    const float* b_hh  = (const float*)d_in[10];
    const float* W_out = (const float*)d_in[11];
    const float* b_out = (const float*)d_in[12];

    float* value = (float*)d_out;
    float* hid   = (float*)d_out + NENV;

    short* WcTB = (short*)d_ws;                          // 2048 bf16
    float* bcw  = (float*)((char*)d_ws + 4096);          // 64 f32
    short* WihB = (short*)((char*)d_ws + 4608);          // 12288 bf16
    short* WhhB = WihB + RD3 * GD;                       // 12288 bf16

    prep_kernel<<<97, 256, 0, stream>>>(W_pre, b_pre, W_gcn, W_ih, W_hh,
                                        WcTB, bcw, WihB, WhhB);
    gcn_kernel<<<NENV / 4, 256, 0, stream>>>(x, edge, bcw, b_gcn, WcTB, hid);
    gru_kernel<<<NENV / 4, 256, 0, stream>>>(h0, WihB, WhhB, b_ih, b_hh,
                                             W_out, b_out, value, hid);
}